// Round 6
// baseline (128.029 us; speedup 1.0000x reference)
//
#include <hip/hip_runtime.h>
#include <hip/hip_fp16.h>

#define NP    128   // planets per batch
#define NH    64    // hidden dim
#define PAIRS 2     // batch-PAIRS per wave (2 batches interleaved) = 4 batches
#define WPB   4     // waves per block

typedef __attribute__((ext_vector_type(8))) _Float16 f16x8;   // K32 MFMA A/B operand
typedef __attribute__((ext_vector_type(4))) _Float16 f16x4;   // K16 MFMA A/B operand
typedef __attribute__((ext_vector_type(2))) __fp16  hf16x2;   // cvt_pkrtz return type
typedef __attribute__((ext_vector_type(4))) float f32x4;

union FragK16 { f16x4 v; unsigned int u[2]; };
union FragK32 { f16x8 v; unsigned int u[4]; };

__device__ __forceinline__ unsigned int pack_pkrtz(float a, float b) {
    hf16x2 t = __builtin_amdgcn_cvt_pkrtz(a, b);
    return __builtin_bit_cast(unsigned int, t);
}

// packed f16 relu (v_pk_max_f16). relu(rtz(x)) == rtz(relu(x)).
__device__ __forceinline__ unsigned int relu2_pk(unsigned int u) {
    hf16x2 h = __builtin_bit_cast(hf16x2, u);
    h = __builtin_elementwise_max(h, (hf16x2)(__fp16)0.f);
    return __builtin_bit_cast(unsigned int, h);
}

// DUAL-CHAIN version. Evidence through R5: duration ~= MFMA-pipe-work +
// VALU-pipe-work (the per-wave chain feat->L1->pack->L2->pack->reduce
// alternates pipes and ~2.6 resident waves/SIMD can't fill the gaps), and
// every stage-pipelining attempt bought ILP with VGPRs and lost more to
// occupancy than it gained (R2 72r -20%, R3 68r -10%, R4 76r -13%).
//
// The register-efficient form of ILP: TWO INDEPENDENT BATCHES per wave,
// interleaved at MFMA-group granularity. ~62 regs of weights (w1f/w2b/b2f/
// pmv) are SHARED between the chains, so the second instruction stream costs
// only ~+35 live regs instead of a full wave's ~170. Interleave order gives
// every MFMA's consumer >=4-8 of the other chain's MFMAs (~100cy+) of slack:
//     L1(A) | L1(B) | packH(A) L2(A) | packH(B) L2(B)
//           | packM(A) red(A) | packM(B) red(B)
// so chain B's MFMAs issue in chain A's latency shadows and vice versa —
// works even with ONE resident wave/SIMD.
//
// Layer structure (unchanged since R1):
//   layer1 16x16x16 (b1 folded as constant-1 feature k=4);
//   sigma(32kk+8q+j)=16*(2kk+(j>>2))+4q+(j&3) makes the K32 layer2 A-operand
//   a pure register concat of layer1 C-fragments (written directly in place);
//   layer2 puts PLANETS on the (q,reg) axis so the relu'd msg tile packed to
//   f16 is directly a 16x16x16 B-frag and the 128-planet reduction is 8
//   accumulating MFMAs against an all-ones A. No LDS, no barriers.
__global__ void __launch_bounds__(256, 2) gnn_wave(
    const float* __restrict__ planet_xy,  // [B][P][2]
    const float* __restrict__ planet_m,   // [P]
    const float* __restrict__ ast_xy,     // [B][2]
    const float* __restrict__ W1,         // [4][64]
    const float* __restrict__ b1,         // [64]
    const float* __restrict__ W2,         // [64][64]
    const float* __restrict__ b2,         // [64]
    float* __restrict__ out)              // [B][64]
{
    const int tid  = threadIdx.x;
    const int wv   = tid >> 6;
    const int lane = tid & 63;
    const int q    = lane >> 4;
    const int lm   = lane & 15;
    const bool q0  = (q == 0);
    const bool q1  = (q == 1);

    // ---- layer1 A-frags (16x16x16), b1 folded as constant-1 feature k=4 ----
    FragK16 w1f[4];
    #pragma unroll
    for (int mt = 0; mt < 4; mt++) {
        const int m = 16 * mt + lm;
        float wa = W1[0 * NH + m], wb = W1[1 * NH + m];
        float wc = W1[2 * NH + m], wd = W1[3 * NH + m];
        float be = b1[m];
        w1f[mt].u[0] = q0 ? pack_pkrtz(wa, wb) : (q1 ? pack_pkrtz(be, 0.f) : 0u);
        w1f[mt].u[1] = q0 ? pack_pkrtz(wc, wd) : 0u;
    }

    // ---- layer2 B-frags (16x16x32), sigma-permuted W2 rows ----
    FragK32 w2b[4][2];   // [np][kk]
    #pragma unroll
    for (int np = 0; np < 4; np++)
        #pragma unroll
        for (int kk = 0; kk < 2; kk++) {
            const int n = 16 * np + lm;
            const int k0 = 32 * kk + 4 * q;        // j>>2 == 0 rows
            const int k1 = 32 * kk + 16 + 4 * q;   // j>>2 == 1 rows
            w2b[np][kk].u[0] = pack_pkrtz(W2[(k0 + 0) * NH + n], W2[(k0 + 1) * NH + n]);
            w2b[np][kk].u[1] = pack_pkrtz(W2[(k0 + 2) * NH + n], W2[(k0 + 3) * NH + n]);
            w2b[np][kk].u[2] = pack_pkrtz(W2[(k1 + 0) * NH + n], W2[(k1 + 1) * NH + n]);
            w2b[np][kk].u[3] = pack_pkrtz(W2[(k1 + 2) * NH + n], W2[(k1 + 3) * NH + n]);
        }

    // b2 as layer2 C-init: output rows are planets, cols n'=16np+lm -> broadcast
    f32x4 b2f[4];
    #pragma unroll
    for (int np = 0; np < 4; np++) {
        const float bv = b2[16 * np + lm];
        b2f[np] = (f32x4){bv, bv, bv, bv};
    }

    // batch-invariant planet masses (planet 16*i + lm)
    float pmv[8];
    #pragma unroll
    for (int i = 0; i < 8; i++)
        pmv[i] = planet_m[16 * i + lm];

    const unsigned int bf0_const = q1 ? pack_pkrtz(1.f, 0.f) : 0u;
    const f32x4 zf = (f32x4){0.f, 0.f, 0.f, 0.f};

    // all-ones A-frag for the planet-reduction MFMA
    FragK16 onesA;
    onesA.u[0] = 0x3C003C00u;   // (1.0h, 1.0h)
    onesA.u[1] = 0x3C003C00u;

    int b = (blockIdx.x * WPB + wv) * (2 * PAIRS);

    #pragma unroll 1
    for (int pr = 0; pr < PAIRS; ++pr, b += 2) {
        const int bA = b, bB = b + 1;

        // ---- load both chains' inputs (one boundary stall per PAIR) ----
        const float2 axA = *(const float2*)&ast_xy[2 * bA];
        const float2 axB = *(const float2*)&ast_xy[2 * bB];
        float2 pxA[8], pxB[8];
        #pragma unroll
        for (int i = 0; i < 8; i++) {
            pxA[i] = *(const float2*)&planet_xy[((size_t)bA * NP + 16 * i + lm) * 2];
            pxB[i] = *(const float2*)&planet_xy[((size_t)bB * NP + 16 * i + lm) * 2];
        }

        f32x4 rdA[4], rdB[4];
        #pragma unroll
        for (int np = 0; np < 4; np++) { rdA[np] = zf; rdB[np] = zf; }

        #pragma unroll
        for (int mi = 0; mi < 8; ++mi) {
            // ---- stage 1: features + layer1 for BOTH chains ----
            f32x4 cA[4], cB[4];
            {
                float dx = pxA[mi].x - axA.x, dy = pxA[mi].y - axA.y;
                float inv = __builtin_amdgcn_rsqf(fmaf(dx, dx, fmaf(dy, dy, 1e-6f)));
                FragK16 bf;
                bf.u[0] = q0 ? pack_pkrtz(dx, dy)        : bf0_const;
                bf.u[1] = q0 ? pack_pkrtz(inv, pmv[mi])  : 0u;
                #pragma unroll
                for (int mt = 0; mt < 4; mt++)
                    cA[mt] = __builtin_amdgcn_mfma_f32_16x16x16f16(w1f[mt].v, bf.v, zf, 0, 0, 0);
            }
            {
                float dx = pxB[mi].x - axB.x, dy = pxB[mi].y - axB.y;
                float inv = __builtin_amdgcn_rsqf(fmaf(dx, dx, fmaf(dy, dy, 1e-6f)));
                FragK16 bf;
                bf.u[0] = q0 ? pack_pkrtz(dx, dy)        : bf0_const;
                bf.u[1] = q0 ? pack_pkrtz(inv, pmv[mi])  : 0u;
                #pragma unroll
                for (int mt = 0; mt < 4; mt++)
                    cB[mt] = __builtin_amdgcn_mfma_f32_16x16x16f16(w1f[mt].v, bf.v, zf, 0, 0, 0);
            }

            // ---- stage 2: pack h + layer2, chain A then chain B ----
            // (cA consumers sit behind cB's 4 MFMAs; accA behind chain B's 8)
            f32x4 accA[4], accB[4];
            {
                FragK32 hA[2];
                #pragma unroll
                for (int mt = 0; mt < 4; mt++) {
                    hA[mt >> 1].u[2 * (mt & 1) + 0] = relu2_pk(pack_pkrtz(cA[mt][0], cA[mt][1]));
                    hA[mt >> 1].u[2 * (mt & 1) + 1] = relu2_pk(pack_pkrtz(cA[mt][2], cA[mt][3]));
                }
                #pragma unroll
                for (int np = 0; np < 4; np++)
                    accA[np] = __builtin_amdgcn_mfma_f32_16x16x32_f16(hA[0].v, w2b[np][0].v, b2f[np], 0, 0, 0);
                #pragma unroll
                for (int np = 0; np < 4; np++)
                    accA[np] = __builtin_amdgcn_mfma_f32_16x16x32_f16(hA[1].v, w2b[np][1].v, accA[np], 0, 0, 0);
            }
            {
                FragK32 hB[2];
                #pragma unroll
                for (int mt = 0; mt < 4; mt++) {
                    hB[mt >> 1].u[2 * (mt & 1) + 0] = relu2_pk(pack_pkrtz(cB[mt][0], cB[mt][1]));
                    hB[mt >> 1].u[2 * (mt & 1) + 1] = relu2_pk(pack_pkrtz(cB[mt][2], cB[mt][3]));
                }
                #pragma unroll
                for (int np = 0; np < 4; np++)
                    accB[np] = __builtin_amdgcn_mfma_f32_16x16x32_f16(hB[0].v, w2b[np][0].v, b2f[np], 0, 0, 0);
                #pragma unroll
                for (int np = 0; np < 4; np++)
                    accB[np] = __builtin_amdgcn_mfma_f32_16x16x32_f16(hB[1].v, w2b[np][1].v, accB[np], 0, 0, 0);
            }

            // ---- stage 3: pack msg + reduce, chain A then chain B ----
            // (accA consumers sit behind chain B's 8 L2 MFMAs)
            {
                FragK16 mf[4];
                #pragma unroll
                for (int np = 0; np < 4; np++) {
                    mf[np].u[0] = relu2_pk(pack_pkrtz(accA[np][0], accA[np][1]));
                    mf[np].u[1] = relu2_pk(pack_pkrtz(accA[np][2], accA[np][3]));
                }
                #pragma unroll
                for (int np = 0; np < 4; np++)
                    rdA[np] = __builtin_amdgcn_mfma_f32_16x16x16f16(onesA.v, mf[np].v, rdA[np], 0, 0, 0);
            }
            {
                FragK16 mf[4];
                #pragma unroll
                for (int np = 0; np < 4; np++) {
                    mf[np].u[0] = relu2_pk(pack_pkrtz(accB[np][0], accB[np][1]));
                    mf[np].u[1] = relu2_pk(pack_pkrtz(accB[np][2], accB[np][3]));
                }
                #pragma unroll
                for (int np = 0; np < 4; np++)
                    rdB[np] = __builtin_amdgcn_mfma_f32_16x16x16f16(onesA.v, mf[np].v, rdB[np], 0, 0, 0);
            }
        }

        // lane 16q+lm needs n' = lane -> select np == q; coalesced b32 stores
        float vA = q0 ? rdA[0][0]
                 : q1 ? rdA[1][0]
                 : (q == 2) ? rdA[2][0] : rdA[3][0];
        float vB = q0 ? rdB[0][0]
                 : q1 ? rdB[1][0]
                 : (q == 2) ? rdB[2][0] : rdB[3][0];
        out[(size_t)bA * NH + lane] = vA;
        out[(size_t)bB * NH + lane] = vB;
    }
}

extern "C" void kernel_launch(void* const* d_in, const int* in_sizes, int n_in,
                              void* d_out, int out_size, void* d_ws, size_t ws_size,
                              hipStream_t stream) {
    const float* planet_xy = (const float*)d_in[0];
    const float* planet_m  = (const float*)d_in[1];
    const float* ast_xy    = (const float*)d_in[2];
    const float* W1        = (const float*)d_in[3];
    const float* b1        = (const float*)d_in[4];
    const float* W2        = (const float*)d_in[5];
    const float* b2        = (const float*)d_in[6];
    float* outp            = (float*)d_out;

    const int B = in_sizes[2] / 2;   // ast_xy is [B][2]
    const int batches_per_block = WPB * 2 * PAIRS;
    const int grid = (B + batches_per_block - 1) / batches_per_block;

    gnn_wave<<<grid, 256, 0, stream>>>(planet_xy, planet_m, ast_xy, W1, b1, W2, b2, outp);
}